// Round 5
// baseline (549.036 us; speedup 1.0000x reference)
//
#include <hip/hip_runtime.h>
#include <stdint.h>

#define B_   2
#define S_   2048
#define D_   2048
#define QH_  32
#define KVH_ 8
#define HD_  64

typedef short  short8  __attribute__((ext_vector_type(8)));
typedef float  floatx4 __attribute__((ext_vector_type(4)));

__device__ __forceinline__ ushort f2b(float f) {
  union { float f; uint32_t u; } c; c.f = f;
  uint32_t u = c.u;
  return (ushort)((u + 0x7FFFu + ((u >> 16) & 1u)) >> 16);
}

__device__ __forceinline__ uint32_t fbits(float f) {
  union { float f; uint32_t u; } c; c.f = f;
  return c.u;
}

// async global->LDS DMA, 16B per lane. LDS dest = wave-uniform base + lane*16.
__device__ __forceinline__ void dma16(const void* g, void* l) {
  __builtin_amdgcn_global_load_lds(
      (const __attribute__((address_space(1))) uint32_t*)(uintptr_t)g,
      (__attribute__((address_space(3))) uint32_t*)(uintptr_t)l, 16, 0, 0);
}

#define QSCALE 0.18033688f   // 1/sqrt(64) * log2(e)

// ---------------- elementwise converts ----------------

__global__ __launch_bounds__(256) void conv_x_kernel(const float* __restrict__ X,
                                                     ushort* __restrict__ Xb) {
  size_t i = ((size_t)blockIdx.x * 256 + threadIdx.x) * 4;
  float4 v = *(const float4*)(X + i);
  ushort4 o;
  o.x = f2b(v.x); o.y = f2b(v.y); o.z = f2b(v.z); o.w = f2b(v.w);
  *(ushort4*)(Xb + i) = o;
}

// Batched transpose+convert: z selects {Wq, Wk, Wv, Wo}. W [K=2048][N] -> Wt [N][K] bf16.
__global__ void tconv_all_kernel(const float* __restrict__ Wq, const float* __restrict__ Wk,
                                 const float* __restrict__ Wv, const float* __restrict__ Wo,
                                 ushort* __restrict__ wqkv, ushort* __restrict__ wo) {
  __shared__ float tile[32][33];
  int z = blockIdx.z;
  const float* W; ushort* Wt; int N;
  if (z == 0)      { W = Wq; Wt = wqkv;                        N = 2048; }
  else if (z == 1) { W = Wk; Wt = wqkv + (size_t)2048 * 2048;  N = 512;  }
  else if (z == 2) { W = Wv; Wt = wqkv + (size_t)2560 * 2048;  N = 512;  }
  else             { W = Wo; Wt = wo;                          N = 2048; }
  int bx = blockIdx.x, by = blockIdx.y;
  if (bx * 32 >= N) return;
  int tx = threadIdx.x, ty = threadIdx.y;
#pragma unroll
  for (int i = 0; i < 32; i += 8)
    tile[ty + i][tx] = W[(size_t)(by * 32 + ty + i) * N + bx * 32 + tx];
  __syncthreads();
#pragma unroll
  for (int i = 0; i < 32; i += 8)
    Wt[(size_t)(bx * 32 + ty + i) * 2048 + by * 32 + tx] = f2b(tile[tx][ty + i]);
}

__global__ void bias_kernel(const float* __restrict__ bq, const float* __restrict__ bk,
                            const float* __restrict__ bv, float* __restrict__ outb) {
  int i = blockIdx.x * 256 + threadIdx.x;
  if (i >= 3072) return;
  float v;
  if (i < 2048)      v = bq[i];
  else if (i < 2560) v = bk[i - 2048];
  else               v = bv[i - 2560];
  outb[i] = v;
}

// ---------------- fused QKV GEMM + bias + RoPE + packed bf16 scatter --------
// Head dim stored PERMUTED: d' = (d&15)*4 + (d>>4). Q,K share the permutation
// (QK^T invariant); V unpermuted later in vpack. Lane's 4 ni-values become
// contiguous -> one ushort4 store per (mi,r): 16 coalesced 8B stores/thread.

__global__ __launch_bounds__(256) void gemm_qkv_kernel(
    const ushort* __restrict__ A, const ushort* __restrict__ Bt,
    const float* __restrict__ bias, const float2* __restrict__ F2,
    ushort* __restrict__ qb, ushort* __restrict__ kb, ushort* __restrict__ vb) {
  const int K = 2048;
  __shared__ ushort sA[2][128 * 32];
  __shared__ ushort sB[2][128 * 32];
  const int tid  = threadIdx.x;
  const int bm   = blockIdx.y, bn = blockIdx.x;
  const int wave = tid >> 6, lane = tid & 63;
  const int quad = lane >> 4, l16 = lane & 15;
  const int wm   = (wave >> 1) * 64, wn = (wave & 1) * 64;

  const ushort* Ab = A  + (size_t)(bm * 128) * K;
  const ushort* Bb = Bt + (size_t)(bn * 128) * K;

  const int gr = lane >> 2;
  const int gu = (lane & 3) * 8;

  floatx4 acc[4][4];
#pragma unroll
  for (int i = 0; i < 4; i++)
#pragma unroll
    for (int j = 0; j < 4; j++) acc[i][j] = (floatx4){0.f, 0.f, 0.f, 0.f};

#pragma unroll
  for (int j = 0; j < 2; j++) {
    int row = j * 64 + wave * 16 + gr;
    dma16(Ab + (size_t)row * K + gu, &sA[0][j * 2048 + wave * 512]);
    dma16(Bb + (size_t)row * K + gu, &sB[0][j * 2048 + wave * 512]);
  }

  int cur = 0;
  for (int k0 = 0; k0 < K; k0 += 32) {
    __syncthreads();
    if (k0 + 32 < K) {
      int nxt = cur ^ 1;
#pragma unroll
      for (int j = 0; j < 2; j++) {
        int row = j * 64 + wave * 16 + gr;
        dma16(Ab + (size_t)row * K + k0 + 32 + gu, &sA[nxt][j * 2048 + wave * 512]);
        dma16(Bb + (size_t)row * K + k0 + 32 + gu, &sB[nxt][j * 2048 + wave * 512]);
      }
    }
    short8 af[4], bf[4];
#pragma unroll
    for (int mi = 0; mi < 4; mi++)
      af[mi] = *(const short8*)&sA[cur][(wm + mi * 16 + l16) * 32 + quad * 8];
#pragma unroll
    for (int ni = 0; ni < 4; ni++)
      bf[ni] = *(const short8*)&sB[cur][(wn + ni * 16 + l16) * 32 + quad * 8];
#pragma unroll
    for (int mi = 0; mi < 4; mi++)
#pragma unroll
      for (int ni = 0; ni < 4; ni++)
        acc[mi][ni] = __builtin_amdgcn_mfma_f32_16x16x32_bf16(
            af[mi], bf[ni], acc[mi][ni], 0, 0, 0);
    cur ^= 1;
  }

  // ---- fused epilogue (packed, permuted-d stores) ----
  const int isQ = (bn < 16);
  const int isV = (bn >= 20);
  const int hh  = wn >> 6;
  const float sySign = (l16 & 1) ? 1.f : -1.f;
  ushort* dst;
  int hbase;
  if (isQ)      { dst = qb; hbase = bn * 2 + hh; }
  else if (!isV){ dst = kb; hbase = (bn - 16) * 2 + hh; }
  else          { dst = vb; hbase = (bn - 20) * 2 + hh; }
  const int NH = isQ ? QH_ : KVH_;

  float bvv[4];
#pragma unroll
  for (int ni = 0; ni < 4; ni++)
    bvv[ni] = bias[bn * 128 + wn + ni * 16 + l16];

#pragma unroll
  for (int mi = 0; mi < 4; mi++) {
#pragma unroll
    for (int r = 0; r < 4; r++) {
      int row = bm * 128 + wm + mi * 16 + quad * 4 + r;
      int s = row & 2047, bb = row >> 11;
      size_t base = (((size_t)bb * NH + hbase) * S_ + s) * HD_ + l16 * 4;
      ushort4 pk;
      if (!isV) {
        float o[4];
#pragma unroll
        for (int ni = 0; ni < 4; ni++) {
          float xv = acc[mi][ni][r] + bvv[ni];
          float2 cs = F2[s * 32 + ni * 8 + (l16 >> 1)];
          float pp = __shfl_xor(xv, 1);
          float oo = fmaf(pp * sySign, cs.y, xv * cs.x);
          if (isQ) oo *= QSCALE;
          o[ni] = oo;
        }
        pk.x = f2b(o[0]); pk.y = f2b(o[1]); pk.z = f2b(o[2]); pk.w = f2b(o[3]);
      } else {
        pk.x = f2b(acc[mi][0][r] + bvv[0]);
        pk.y = f2b(acc[mi][1][r] + bvv[1]);
        pk.z = f2b(acc[mi][2][r] + bvv[2]);
        pk.w = f2b(acc[mi][3][r] + bvv[3]);
      }
      *(ushort4*)&dst[base] = pk;
    }
  }
}

// ---------------- GEMM: C[M][N] = A @ Bt^T + bias (fp32 out) ----------------

__global__ __launch_bounds__(256) void gemm_bt_kernel(
    const ushort* __restrict__ A, const ushort* __restrict__ Bt,
    const float* __restrict__ bias, float* __restrict__ C,
    int M, int N, int K) {
  __shared__ ushort sA[2][128 * 32];
  __shared__ ushort sB[2][128 * 32];
  const int tid  = threadIdx.x;
  const int bm   = blockIdx.y, bn = blockIdx.x;
  const int wave = tid >> 6, lane = tid & 63;
  const int quad = lane >> 4, l16 = lane & 15;
  const int wm   = (wave >> 1) * 64, wn = (wave & 1) * 64;

  const ushort* Ab = A  + (size_t)(bm * 128) * K;
  const ushort* Bb = Bt + (size_t)(bn * 128) * K;

  const int gr = lane >> 2;
  const int gu = (lane & 3) * 8;

  floatx4 acc[4][4];
#pragma unroll
  for (int i = 0; i < 4; i++)
#pragma unroll
    for (int j = 0; j < 4; j++) acc[i][j] = (floatx4){0.f, 0.f, 0.f, 0.f};

#pragma unroll
  for (int j = 0; j < 2; j++) {
    int row = j * 64 + wave * 16 + gr;
    dma16(Ab + (size_t)row * K + gu, &sA[0][j * 2048 + wave * 512]);
    dma16(Bb + (size_t)row * K + gu, &sB[0][j * 2048 + wave * 512]);
  }

  int cur = 0;
  for (int k0 = 0; k0 < K; k0 += 32) {
    __syncthreads();
    if (k0 + 32 < K) {
      int nxt = cur ^ 1;
#pragma unroll
      for (int j = 0; j < 2; j++) {
        int row = j * 64 + wave * 16 + gr;
        dma16(Ab + (size_t)row * K + k0 + 32 + gu, &sA[nxt][j * 2048 + wave * 512]);
        dma16(Bb + (size_t)row * K + k0 + 32 + gu, &sB[nxt][j * 2048 + wave * 512]);
      }
    }
    short8 af[4], bf[4];
#pragma unroll
    for (int mi = 0; mi < 4; mi++)
      af[mi] = *(const short8*)&sA[cur][(wm + mi * 16 + l16) * 32 + quad * 8];
#pragma unroll
    for (int ni = 0; ni < 4; ni++)
      bf[ni] = *(const short8*)&sB[cur][(wn + ni * 16 + l16) * 32 + quad * 8];
#pragma unroll
    for (int mi = 0; mi < 4; mi++)
#pragma unroll
      for (int ni = 0; ni < 4; ni++)
        acc[mi][ni] = __builtin_amdgcn_mfma_f32_16x16x32_bf16(
            af[mi], bf[ni], acc[mi][ni], 0, 0, 0);
    cur ^= 1;
  }

#pragma unroll
  for (int mi = 0; mi < 4; mi++) {
#pragma unroll
    for (int ni = 0; ni < 4; ni++) {
      int col  = bn * 128 + wn + ni * 16 + l16;
      float bv = bias[col];
#pragma unroll
      for (int r = 0; r < 4; r++) {
        int row = bm * 128 + wm + mi * 16 + quad * 4 + r;
        C[(size_t)row * N + col] = acc[mi][ni][r] + bv;
      }
    }
  }
}

// ---------------- V pack: vb [B][KVH][S][64 d'] -> Vt [B][KVH][64 d][S kv'] --
// Reads vb's permuted d-axis (d = (d'&3)*16 + (d'>>2)); writes true-d rows with
// the kv-axis permutation o -> (o&15)*4 + (o>>4) matching the attn P layout.

__global__ void vpack_kernel(const ushort* __restrict__ vb, ushort* __restrict__ Vt) {
  __shared__ ushort tile[64][65];
  int s0 = blockIdx.x * 64;
  int bh = blockIdx.y;
  int tx = threadIdx.x, ty = threadIdx.y;
#pragma unroll
  for (int i = 0; i < 64; i += 8)
    tile[ty + i][tx] = vb[((size_t)bh * S_ + s0 + ty + i) * HD_ + tx];
  __syncthreads();
  int pt = (tx & 15) * 4 + (tx >> 4);   // kv permutation
#pragma unroll
  for (int i = 0; i < 64; i += 8) {
    int dp = ty + i;                    // stored (permuted) d index
    int dt = (dp & 3) * 16 + (dp >> 2); // true d
    Vt[((size_t)bh * HD_ + dt) * S_ + s0 + pt] = tile[tx][dp];
  }
}

// ---------------- Flash attention ----------------
// grid (8, 32, 2), block 512 (8 waves). Wave: 32 q rows (2 m-tiles).
// K chunks (64 kv) double-buffered in LDS via global_load_lds (XOR-swizzled);
// V fragments read DIRECTLY from global (L2-served; issued at top of iter,
// used ~1 iter later in program order -> latency hidden). P via per-wave LDS.

__global__ __launch_bounds__(512, 4) void attn_kernel(
    const ushort* __restrict__ Q, const ushort* __restrict__ K,
    const ushort* __restrict__ Vt, ushort* __restrict__ O) {
  const int qt = blockIdx.x, qh = blockIdx.y, b = blockIdx.z;
  const int kvh = qh >> 2;
  const int tid = threadIdx.x;
  const int wave = tid >> 6, lane = tid & 63;
  const int quad = lane >> 4, l16 = lane & 15;

  __shared__ ushort kBuf[2][64 * 64];   // 16 KB
  __shared__ ushort P[8][16 * 72];      // 18 KB

  const ushort* Qh = Q  + ((size_t)(b * QH_ + qh)) * S_ * HD_;
  const ushort* Kh = K  + ((size_t)(b * KVH_ + kvh)) * S_ * HD_;
  const ushort* Vh = Vt + ((size_t)(b * KVH_ + kvh)) * HD_ * S_ + (size_t)l16 * S_ + quad * 8;

  const int dr = lane >> 3;
  const int du = (lane & 7) ^ (dr & 7);
  const size_t kLaneOff = (size_t)(wave * 8 + dr) * 64 + du * 8;
  const int swz = (l16 & 7);

  const int q0 = qt * 256 + wave * 32;
  short8 aq[2][2];
#pragma unroll
  for (int m = 0; m < 2; m++)
#pragma unroll
    for (int s2 = 0; s2 < 2; s2++)
      aq[m][s2] = *(const short8*)(Qh + (size_t)(q0 + m * 16 + l16) * HD_ + s2 * 32 + quad * 8);

  floatx4 oacc[2][4];
#pragma unroll
  for (int m = 0; m < 2; m++)
#pragma unroll
    for (int t = 0; t < 4; t++) oacc[m][t] = (floatx4){0.f, 0.f, 0.f, 0.f};
  float ls[2][4] = {{0.f, 0.f, 0.f, 0.f}, {0.f, 0.f, 0.f, 0.f}};

  dma16(Kh + kLaneOff, &kBuf[0][wave * 512]);

  int cur = 0;
  for (int kv0 = 0; kv0 < S_; kv0 += 64) {
    __syncthreads();
    if (kv0 + 64 < S_) {
      int nxt = cur ^ 1;
      dma16(Kh + (size_t)(kv0 + 64) * 64 + kLaneOff, &kBuf[nxt][wave * 512]);
    }

    // V fragments direct from global (issued early; used in PV phase)
    short8 vf[2][4];
#pragma unroll
    for (int s2 = 0; s2 < 2; s2++)
#pragma unroll
      for (int t = 0; t < 4; t++)
        vf[s2][t] = *(const short8*)(Vh + (size_t)(t * 16) * S_ + kv0 + s2 * 32);

    // K fragments from LDS (shared across both m-tiles)
    short8 kf[4][2];
#pragma unroll
    for (int c = 0; c < 4; c++)
#pragma unroll
      for (int s2 = 0; s2 < 2; s2++)
        kf[c][s2] = *(const short8*)&kBuf[cur][(c * 16 + l16) * 64 + (((s2 * 4 + quad) ^ swz) * 8)];

#pragma unroll
    for (int m = 0; m < 2; m++) {
      floatx4 sc[4];
#pragma unroll
      for (int c = 0; c < 4; c++) sc[c] = (floatx4){0.f, 0.f, 0.f, 0.f};
#pragma unroll
      for (int c = 0; c < 4; c++)
#pragma unroll
        for (int s2 = 0; s2 < 2; s2++)
          sc[c] = __builtin_amdgcn_mfma_f32_16x16x32_bf16(aq[m][s2], kf[c][s2], sc[c], 0, 0, 0);

#pragma unroll
      for (int r = 0; r < 4; r++) {
        float p0 = __builtin_amdgcn_exp2f(sc[0][r]);
        float p1 = __builtin_amdgcn_exp2f(sc[1][r]);
        float p2 = __builtin_amdgcn_exp2f(sc[2][r]);
        float p3 = __builtin_amdgcn_exp2f(sc[3][r]);
        ls[m][r] += (p0 + p1) + (p2 + p3);
        uint2 u;
        u.x = __builtin_amdgcn_perm(fbits(p1) + 0x8000u, fbits(p0) + 0x8000u, 0x07060302u);
        u.y = __builtin_amdgcn_perm(fbits(p3) + 0x8000u, fbits(p2) + 0x8000u, 0x07060302u);
        *(uint2*)&P[wave][(quad * 4 + r) * 72 + l16 * 4] = u;
      }

#pragma unroll
      for (int s2 = 0; s2 < 2; s2++) {
        short8 ap = *(const short8*)&P[wave][l16 * 72 + s2 * 32 + quad * 8];
#pragma unroll
        for (int t = 0; t < 4; t++)
          oacc[m][t] = __builtin_amdgcn_mfma_f32_16x16x32_bf16(ap, vf[s2][t], oacc[m][t], 0, 0, 0);
      }
    }
    cur ^= 1;
  }

#pragma unroll
  for (int m = 0; m < 2; m++) {
#pragma unroll
    for (int r = 0; r < 4; r++) {
      float l = ls[m][r];
#pragma unroll
      for (int st = 1; st < 16; st <<= 1) l += __shfl_xor(l, st, 16);
      float inv = 1.0f / l;
      int srow = q0 + m * 16 + quad * 4 + r;
      size_t base = ((size_t)b * S_ + srow) * (QH_ * HD_) + (size_t)qh * HD_;
#pragma unroll
      for (int t = 0; t < 4; t++)
        O[base + t * 16 + l16] = f2b(oacc[m][t][r] * inv);
    }
  }
}

// ---------------- launch ----------------

extern "C" void kernel_launch(void* const* d_in, const int* in_sizes, int n_in,
                              void* d_out, int out_size, void* d_ws, size_t ws_size,
                              hipStream_t stream) {
  const float* x  = (const float*)d_in[0];
  const float* fr = (const float*)d_in[1];
  const float* Wq = (const float*)d_in[2];
  const float* bq = (const float*)d_in[3];
  const float* Wk = (const float*)d_in[4];
  const float* bk = (const float*)d_in[5];
  const float* Wv = (const float*)d_in[6];
  const float* bv = (const float*)d_in[7];
  const float* Wo = (const float*)d_in[8];
  const float* bo = (const float*)d_in[9];
  float* out = (float*)d_out;
  char* ws = (char*)d_ws;

  ushort* xb    = (ushort*)(ws + 0);           // 16,777,216  x bf16 (reused as Ob)
  ushort* wqkv  = (ushort*)(ws + 16777216);    // 12,582,912
  ushort* wo    = (ushort*)(ws + 29360128);    //  8,388,608
  float*  biasq = (float* )(ws + 37748736);    //     12,288
  ushort* qb    = (ushort*)(ws + 37761024);    // 16,777,216  Q roped bf16 (perm d)
  ushort* kb    = (ushort*)(ws + 54538240);    //  4,194,304  K roped bf16 (perm d)
  ushort* vb    = (ushort*)(ws + 58732544);    //  4,194,304  V bf16 (perm d)
  ushort* vt    = (ushort*)(ws + 62926848);    //  4,194,304  V [d][s] (perm kv)
  ushort* ob    = xb;                          // alias: xb dead after gemm1

  conv_x_kernel<<<8192, 256, 0, stream>>>(x, xb);
  tconv_all_kernel<<<dim3(64, 64, 4), dim3(32, 8), 0, stream>>>(Wq, Wk, Wv, Wo, wqkv, wo);
  bias_kernel<<<12, 256, 0, stream>>>(bq, bk, bv, biasq);

  gemm_qkv_kernel<<<dim3(3072 / 128, 4096 / 128), 256, 0, stream>>>(
      xb, wqkv, biasq, (const float2*)fr, qb, kb, vb);

  vpack_kernel<<<dim3(2048 / 64, 16), dim3(64, 8), 0, stream>>>(vb, vt);

  attn_kernel<<<dim3(8, 32, 2), 512, 0, stream>>>(qb, kb, vt, ob);

  gemm_bt_kernel<<<dim3(2048 / 128, 4096 / 128), 256, 0, stream>>>(
      ob, wo, bo, out, 4096, 2048, 2048);
}

// Round 6
// 323.218 us; speedup vs baseline: 1.6987x; 1.6987x over previous
//
#include <hip/hip_runtime.h>
#include <stdint.h>

#define B_   2
#define S_   2048
#define D_   2048
#define QH_  32
#define KVH_ 8
#define HD_  64

typedef short  short8  __attribute__((ext_vector_type(8)));
typedef float  floatx4 __attribute__((ext_vector_type(4)));

__device__ __forceinline__ ushort f2b(float f) {
  union { float f; uint32_t u; } c; c.f = f;
  uint32_t u = c.u;
  return (ushort)((u + 0x7FFFu + ((u >> 16) & 1u)) >> 16);
}

__device__ __forceinline__ uint32_t fbits(float f) {
  union { float f; uint32_t u; } c; c.f = f;
  return c.u;
}

__device__ __forceinline__ short8 mk8(uint32_t a, uint32_t b, uint32_t c, uint32_t d) {
  union { uint4 u; short8 s; } v; v.u = (uint4){a, b, c, d}; return v.s;
}

// async global->LDS DMA, 16B per lane. LDS dest = wave-uniform base + lane*16.
__device__ __forceinline__ void dma16(const void* g, void* l) {
  __builtin_amdgcn_global_load_lds(
      (const __attribute__((address_space(1))) uint32_t*)(uintptr_t)g,
      (__attribute__((address_space(3))) uint32_t*)(uintptr_t)l, 16, 0, 0);
}

#define QSCALE 0.18033688f   // 1/sqrt(64) * log2(e)

// ---------------- elementwise converts ----------------

__global__ __launch_bounds__(256) void conv_x_kernel(const float* __restrict__ X,
                                                     ushort* __restrict__ Xb) {
  size_t i = ((size_t)blockIdx.x * 256 + threadIdx.x) * 4;
  float4 v = *(const float4*)(X + i);
  ushort4 o;
  o.x = f2b(v.x); o.y = f2b(v.y); o.z = f2b(v.z); o.w = f2b(v.w);
  *(ushort4*)(Xb + i) = o;
}

// Batched transpose+convert: z selects {Wq, Wk, Wv, Wo}. W [K=2048][N] -> Wt [N][K] bf16.
__global__ void tconv_all_kernel(const float* __restrict__ Wq, const float* __restrict__ Wk,
                                 const float* __restrict__ Wv, const float* __restrict__ Wo,
                                 ushort* __restrict__ wqkv, ushort* __restrict__ wo) {
  __shared__ float tile[32][33];
  int z = blockIdx.z;
  const float* W; ushort* Wt; int N;
  if (z == 0)      { W = Wq; Wt = wqkv;                        N = 2048; }
  else if (z == 1) { W = Wk; Wt = wqkv + (size_t)2048 * 2048;  N = 512;  }
  else if (z == 2) { W = Wv; Wt = wqkv + (size_t)2560 * 2048;  N = 512;  }
  else             { W = Wo; Wt = wo;                          N = 2048; }
  int bx = blockIdx.x, by = blockIdx.y;
  if (bx * 32 >= N) return;
  int tx = threadIdx.x, ty = threadIdx.y;
#pragma unroll
  for (int i = 0; i < 32; i += 8)
    tile[ty + i][tx] = W[(size_t)(by * 32 + ty + i) * N + bx * 32 + tx];
  __syncthreads();
#pragma unroll
  for (int i = 0; i < 32; i += 8)
    Wt[(size_t)(bx * 32 + ty + i) * 2048 + by * 32 + tx] = f2b(tile[tx][ty + i]);
}

__global__ void bias_kernel(const float* __restrict__ bq, const float* __restrict__ bk,
                            const float* __restrict__ bv, float* __restrict__ outb) {
  int i = blockIdx.x * 256 + threadIdx.x;
  if (i >= 3072) return;
  float v;
  if (i < 2048)      v = bq[i];
  else if (i < 2560) v = bk[i - 2048];
  else               v = bv[i - 2560];
  outb[i] = v;
}

// ---------------- fused QKV GEMM + bias + RoPE + packed bf16 scatter --------
// Head dim stored PERMUTED: d' = (d&15)*4 + (d>>4). Q,K share the permutation
// (QK^T invariant); V unpermuted later in vpack.

__global__ __launch_bounds__(256) void gemm_qkv_kernel(
    const ushort* __restrict__ A, const ushort* __restrict__ Bt,
    const float* __restrict__ bias, const float2* __restrict__ F2,
    ushort* __restrict__ qb, ushort* __restrict__ kb, ushort* __restrict__ vb) {
  const int K = 2048;
  __shared__ ushort sA[2][128 * 32];
  __shared__ ushort sB[2][128 * 32];
  const int tid  = threadIdx.x;
  const int bm   = blockIdx.y, bn = blockIdx.x;
  const int wave = tid >> 6, lane = tid & 63;
  const int quad = lane >> 4, l16 = lane & 15;
  const int wm   = (wave >> 1) * 64, wn = (wave & 1) * 64;

  const ushort* Ab = A  + (size_t)(bm * 128) * K;
  const ushort* Bb = Bt + (size_t)(bn * 128) * K;

  const int gr = lane >> 2;
  const int gu = (lane & 3) * 8;

  floatx4 acc[4][4];
#pragma unroll
  for (int i = 0; i < 4; i++)
#pragma unroll
    for (int j = 0; j < 4; j++) acc[i][j] = (floatx4){0.f, 0.f, 0.f, 0.f};

#pragma unroll
  for (int j = 0; j < 2; j++) {
    int row = j * 64 + wave * 16 + gr;
    dma16(Ab + (size_t)row * K + gu, &sA[0][j * 2048 + wave * 512]);
    dma16(Bb + (size_t)row * K + gu, &sB[0][j * 2048 + wave * 512]);
  }

  int cur = 0;
  for (int k0 = 0; k0 < K; k0 += 32) {
    __syncthreads();
    if (k0 + 32 < K) {
      int nxt = cur ^ 1;
#pragma unroll
      for (int j = 0; j < 2; j++) {
        int row = j * 64 + wave * 16 + gr;
        dma16(Ab + (size_t)row * K + k0 + 32 + gu, &sA[nxt][j * 2048 + wave * 512]);
        dma16(Bb + (size_t)row * K + k0 + 32 + gu, &sB[nxt][j * 2048 + wave * 512]);
      }
    }
    short8 af[4], bf[4];
#pragma unroll
    for (int mi = 0; mi < 4; mi++)
      af[mi] = *(const short8*)&sA[cur][(wm + mi * 16 + l16) * 32 + quad * 8];
#pragma unroll
    for (int ni = 0; ni < 4; ni++)
      bf[ni] = *(const short8*)&sB[cur][(wn + ni * 16 + l16) * 32 + quad * 8];
#pragma unroll
    for (int mi = 0; mi < 4; mi++)
#pragma unroll
      for (int ni = 0; ni < 4; ni++)
        acc[mi][ni] = __builtin_amdgcn_mfma_f32_16x16x32_bf16(
            af[mi], bf[ni], acc[mi][ni], 0, 0, 0);
    cur ^= 1;
  }

  // ---- fused epilogue (packed, permuted-d stores) ----
  const int isQ = (bn < 16);
  const int isV = (bn >= 20);
  const int hh  = wn >> 6;
  const float sySign = (l16 & 1) ? 1.f : -1.f;
  ushort* dst;
  int hbase;
  if (isQ)      { dst = qb; hbase = bn * 2 + hh; }
  else if (!isV){ dst = kb; hbase = (bn - 16) * 2 + hh; }
  else          { dst = vb; hbase = (bn - 20) * 2 + hh; }
  const int NH = isQ ? QH_ : KVH_;

  float bvv[4];
#pragma unroll
  for (int ni = 0; ni < 4; ni++)
    bvv[ni] = bias[bn * 128 + wn + ni * 16 + l16];

#pragma unroll
  for (int mi = 0; mi < 4; mi++) {
#pragma unroll
    for (int r = 0; r < 4; r++) {
      int row = bm * 128 + wm + mi * 16 + quad * 4 + r;
      int s = row & 2047, bb = row >> 11;
      size_t base = (((size_t)bb * NH + hbase) * S_ + s) * HD_ + l16 * 4;
      ushort4 pk;
      if (!isV) {
        float o[4];
#pragma unroll
        for (int ni = 0; ni < 4; ni++) {
          float xv = acc[mi][ni][r] + bvv[ni];
          float2 cs = F2[s * 32 + ni * 8 + (l16 >> 1)];
          float pp = __shfl_xor(xv, 1);
          float oo = fmaf(pp * sySign, cs.y, xv * cs.x);
          if (isQ) oo *= QSCALE;
          o[ni] = oo;
        }
        pk.x = f2b(o[0]); pk.y = f2b(o[1]); pk.z = f2b(o[2]); pk.w = f2b(o[3]);
      } else {
        pk.x = f2b(acc[mi][0][r] + bvv[0]);
        pk.y = f2b(acc[mi][1][r] + bvv[1]);
        pk.z = f2b(acc[mi][2][r] + bvv[2]);
        pk.w = f2b(acc[mi][3][r] + bvv[3]);
      }
      *(ushort4*)&dst[base] = pk;
    }
  }
}

// ---------------- GEMM: C[M][N] = A @ Bt^T + bias (fp32 out) ----------------

__global__ __launch_bounds__(256) void gemm_bt_kernel(
    const ushort* __restrict__ A, const ushort* __restrict__ Bt,
    const float* __restrict__ bias, float* __restrict__ C,
    int M, int N, int K) {
  __shared__ ushort sA[2][128 * 32];
  __shared__ ushort sB[2][128 * 32];
  const int tid  = threadIdx.x;
  const int bm   = blockIdx.y, bn = blockIdx.x;
  const int wave = tid >> 6, lane = tid & 63;
  const int quad = lane >> 4, l16 = lane & 15;
  const int wm   = (wave >> 1) * 64, wn = (wave & 1) * 64;

  const ushort* Ab = A  + (size_t)(bm * 128) * K;
  const ushort* Bb = Bt + (size_t)(bn * 128) * K;

  const int gr = lane >> 2;
  const int gu = (lane & 3) * 8;

  floatx4 acc[4][4];
#pragma unroll
  for (int i = 0; i < 4; i++)
#pragma unroll
    for (int j = 0; j < 4; j++) acc[i][j] = (floatx4){0.f, 0.f, 0.f, 0.f};

#pragma unroll
  for (int j = 0; j < 2; j++) {
    int row = j * 64 + wave * 16 + gr;
    dma16(Ab + (size_t)row * K + gu, &sA[0][j * 2048 + wave * 512]);
    dma16(Bb + (size_t)row * K + gu, &sB[0][j * 2048 + wave * 512]);
  }

  int cur = 0;
  for (int k0 = 0; k0 < K; k0 += 32) {
    __syncthreads();
    if (k0 + 32 < K) {
      int nxt = cur ^ 1;
#pragma unroll
      for (int j = 0; j < 2; j++) {
        int row = j * 64 + wave * 16 + gr;
        dma16(Ab + (size_t)row * K + k0 + 32 + gu, &sA[nxt][j * 2048 + wave * 512]);
        dma16(Bb + (size_t)row * K + k0 + 32 + gu, &sB[nxt][j * 2048 + wave * 512]);
      }
    }
    short8 af[4], bf[4];
#pragma unroll
    for (int mi = 0; mi < 4; mi++)
      af[mi] = *(const short8*)&sA[cur][(wm + mi * 16 + l16) * 32 + quad * 8];
#pragma unroll
    for (int ni = 0; ni < 4; ni++)
      bf[ni] = *(const short8*)&sB[cur][(wn + ni * 16 + l16) * 32 + quad * 8];
#pragma unroll
    for (int mi = 0; mi < 4; mi++)
#pragma unroll
      for (int ni = 0; ni < 4; ni++)
        acc[mi][ni] = __builtin_amdgcn_mfma_f32_16x16x32_bf16(
            af[mi], bf[ni], acc[mi][ni], 0, 0, 0);
    cur ^= 1;
  }

#pragma unroll
  for (int mi = 0; mi < 4; mi++) {
#pragma unroll
    for (int ni = 0; ni < 4; ni++) {
      int col  = bn * 128 + wn + ni * 16 + l16;
      float bv = bias[col];
#pragma unroll
      for (int r = 0; r < 4; r++) {
        int row = bm * 128 + wm + mi * 16 + quad * 4 + r;
        C[(size_t)row * N + col] = acc[mi][ni][r] + bv;
      }
    }
  }
}

// ---------------- V pack: vb [B][KVH][S][64 d'] -> Vt [B][KVH][64 d][S kv] --
// Un-permutes d (d = (d'&3)*16 + (d'>>2)); kv axis in NATURAL order.

__global__ void vpack_kernel(const ushort* __restrict__ vb, ushort* __restrict__ Vt) {
  __shared__ ushort tile[64][65];
  int s0 = blockIdx.x * 64;
  int bh = blockIdx.y;
  int tx = threadIdx.x, ty = threadIdx.y;
#pragma unroll
  for (int i = 0; i < 64; i += 8)
    tile[ty + i][tx] = vb[((size_t)bh * S_ + s0 + ty + i) * HD_ + tx];
  __syncthreads();
#pragma unroll
  for (int i = 0; i < 64; i += 8) {
    int dp = ty + i;                    // stored (permuted) d index
    int dt = (dp & 3) * 16 + (dp >> 2); // true d
    Vt[((size_t)bh * HD_ + dt) * S_ + s0 + tx] = tile[tx][dp];
  }
}

// ---------------- Flash attention (register P, no LDS round-trip) ----------
// grid (4, 32, 2), block 512 (8 waves), 1 block/CU. Wave: 64 q rows (4 m-tiles).
// S^T = mfma(A=K_frag, B=Q_frag) puts kv at quad*4+r, q at l16 -> exp2'd
// registers ARE the PV A-fragment (k-slot quad*8+j = kv half*16+quad*4+j).
// V read from vBuf [d][kv] as two b64s with the same k-slot mapping.
// K,V chunks double-buffered via global_load_lds; one barrier/iter.

__global__ __launch_bounds__(512, 2) void attn_kernel(
    const ushort* __restrict__ Q, const ushort* __restrict__ K,
    const ushort* __restrict__ Vt, ushort* __restrict__ O) {
  const int qt = blockIdx.x, qh = blockIdx.y, b = blockIdx.z;
  const int kvh = qh >> 2;
  const int tid = threadIdx.x;
  const int wave = tid >> 6, lane = tid & 63;
  const int quad = lane >> 4, l16 = lane & 15;

  __shared__ ushort kBuf[2][64 * 64];   // 16 KB
  __shared__ ushort vBuf[2][64 * 64];   // 16 KB

  const ushort* Qh = Q  + ((size_t)(b * QH_ + qh)) * S_ * HD_;
  const ushort* Kh = K  + ((size_t)(b * KVH_ + kvh)) * S_ * HD_;
  const ushort* Vh = Vt + ((size_t)(b * KVH_ + kvh)) * HD_ * S_;

  const int dr = lane >> 3;
  const int du = (lane & 7) ^ (dr & 7);
  const size_t kLaneOff = (size_t)(wave * 8 + dr) * 64 + du * 8;
  const size_t vLaneOff = (size_t)(wave * 8 + dr) * S_ + du * 8;
  const int swz = l16 & 7;

  const int q0 = (qt * 8 + wave) * 64;
  short8 aq[4][2];
#pragma unroll
  for (int m = 0; m < 4; m++)
#pragma unroll
    for (int s2 = 0; s2 < 2; s2++)
      aq[m][s2] = *(const short8*)(Qh + (size_t)(q0 + m * 16 + l16) * HD_ + s2 * 32 + quad * 8);

  floatx4 oacc[4][4];
#pragma unroll
  for (int m = 0; m < 4; m++)
#pragma unroll
    for (int t = 0; t < 4; t++) oacc[m][t] = (floatx4){0.f, 0.f, 0.f, 0.f};
  float ls[4] = {0.f, 0.f, 0.f, 0.f};

  dma16(Kh + kLaneOff, &kBuf[0][wave * 512]);
  dma16(Vh + vLaneOff, &vBuf[0][wave * 512]);

  int cur = 0;
  for (int kv0 = 0; kv0 < S_; kv0 += 64) {
    __syncthreads();
    if (kv0 + 64 < S_) {
      int nxt = cur ^ 1;
      dma16(Kh + (size_t)(kv0 + 64) * 64 + kLaneOff, &kBuf[nxt][wave * 512]);
      dma16(Vh + (size_t)(kv0 + 64) + vLaneOff,      &vBuf[nxt][wave * 512]);
    }

#pragma unroll
    for (int u = 0; u < 2; u++) {
      uint32_t pk[4][4];   // [m][word]: PV A-fragment words
#pragma unroll
      for (int cc = 0; cc < 2; cc++) {
        const int c = u * 2 + cc;
        short8 kf0 = *(const short8*)&kBuf[cur][(c * 16 + l16) * 64 + ((quad ^ swz) * 8)];
        short8 kf1 = *(const short8*)&kBuf[cur][(c * 16 + l16) * 64 + (((4 + quad) ^ swz) * 8)];
#pragma unroll
        for (int m = 0; m < 4; m++) {
          floatx4 sc = (floatx4){0.f, 0.f, 0.f, 0.f};
          sc = __builtin_amdgcn_mfma_f32_16x16x32_bf16(kf0, aq[m][0], sc, 0, 0, 0);
          sc = __builtin_amdgcn_mfma_f32_16x16x32_bf16(kf1, aq[m][1], sc, 0, 0, 0);
          float p0 = __builtin_amdgcn_exp2f(sc[0]);
          float p1 = __builtin_amdgcn_exp2f(sc[1]);
          float p2 = __builtin_amdgcn_exp2f(sc[2]);
          float p3 = __builtin_amdgcn_exp2f(sc[3]);
          ls[m] += (p0 + p1) + (p2 + p3);
          pk[m][cc * 2 + 0] = __builtin_amdgcn_perm(fbits(p1) + 0x8000u, fbits(p0) + 0x8000u, 0x07060302u);
          pk[m][cc * 2 + 1] = __builtin_amdgcn_perm(fbits(p3) + 0x8000u, fbits(p2) + 0x8000u, 0x07060302u);
        }
      }
#pragma unroll
      for (int t = 0; t < 4; t++) {
        const int row = (t * 16 + l16) * 64;
        uint2 v0 = *(const uint2*)&vBuf[cur][row + (((u * 4 + (quad >> 1)) ^ swz) * 8) + (quad & 1) * 4];
        uint2 v1 = *(const uint2*)&vBuf[cur][row + (((u * 4 + 2 + (quad >> 1)) ^ swz) * 8) + (quad & 1) * 4];
        short8 vf = mk8(v0.x, v0.y, v1.x, v1.y);
#pragma unroll
        for (int m = 0; m < 4; m++) {
          short8 ap = mk8(pk[m][0], pk[m][1], pk[m][2], pk[m][3]);
          oacc[m][t] = __builtin_amdgcn_mfma_f32_16x16x32_bf16(ap, vf, oacc[m][t], 0, 0, 0);
        }
      }
    }
    cur ^= 1;
  }

  // l: per-lane partials are for q=l16, summed over this lane's kv slots.
  // Reduce across quads, then fetch the value for q = quad*4+r via shuffle.
#pragma unroll
  for (int m = 0; m < 4; m++) {
    ls[m] += __shfl_xor(ls[m], 16);
    ls[m] += __shfl_xor(ls[m], 32);
  }
#pragma unroll
  for (int m = 0; m < 4; m++) {
#pragma unroll
    for (int r = 0; r < 4; r++) {
      float l = __shfl(ls[m], (lane & 48) | (quad * 4 + r));
      float inv = 1.0f / l;
      int srow = q0 + m * 16 + quad * 4 + r;
      size_t base = ((size_t)b * S_ + srow) * (QH_ * HD_) + (size_t)qh * HD_;
#pragma unroll
      for (int t = 0; t < 4; t++)
        O[base + t * 16 + l16] = f2b(oacc[m][t][r] * inv);
    }
  }
}

// ---------------- launch ----------------

extern "C" void kernel_launch(void* const* d_in, const int* in_sizes, int n_in,
                              void* d_out, int out_size, void* d_ws, size_t ws_size,
                              hipStream_t stream) {
  const float* x  = (const float*)d_in[0];
  const float* fr = (const float*)d_in[1];
  const float* Wq = (const float*)d_in[2];
  const float* bq = (const float*)d_in[3];
  const float* Wk = (const float*)d_in[4];
  const float* bk = (const float*)d_in[5];
  const float* Wv = (const float*)d_in[6];
  const float* bv = (const float*)d_in[7];
  const float* Wo = (const float*)d_in[8];
  const float* bo = (const float*)d_in[9];
  float* out = (float*)d_out;
  char* ws = (char*)d_ws;

  ushort* xb    = (ushort*)(ws + 0);           // 16,777,216  x bf16 (reused as Ob)
  ushort* wqkv  = (ushort*)(ws + 16777216);    // 12,582,912
  ushort* wo    = (ushort*)(ws + 29360128);    //  8,388,608
  float*  biasq = (float* )(ws + 37748736);    //     12,288
  ushort* qb    = (ushort*)(ws + 37761024);    // 16,777,216  Q roped bf16 (perm d)
  ushort* kb    = (ushort*)(ws + 54538240);    //  4,194,304  K roped bf16 (perm d)
  ushort* vb    = (ushort*)(ws + 58732544);    //  4,194,304  V bf16 (perm d)
  ushort* vt    = (ushort*)(ws + 62926848);    //  4,194,304  V [d][s] true-d
  ushort* ob    = xb;                          // alias: xb dead after gemm1

  conv_x_kernel<<<8192, 256, 0, stream>>>(x, xb);
  tconv_all_kernel<<<dim3(64, 64, 4), dim3(32, 8), 0, stream>>>(Wq, Wk, Wv, Wo, wqkv, wo);
  bias_kernel<<<12, 256, 0, stream>>>(bq, bk, bv, biasq);

  gemm_qkv_kernel<<<dim3(3072 / 128, 4096 / 128), 256, 0, stream>>>(
      xb, wqkv, biasq, (const float2*)fr, qb, kb, vb);

  vpack_kernel<<<dim3(2048 / 64, 16), dim3(64, 8), 0, stream>>>(vb, vt);

  attn_kernel<<<dim3(4, 32, 2), 512, 0, stream>>>(qb, kb, vt, ob);

  gemm_bt_kernel<<<dim3(2048 / 128, 4096 / 128), 256, 0, stream>>>(
      ob, wo, bo, out, 4096, 2048, 2048);
}